// Round 2
// baseline (1176.441 us; speedup 1.0000x reference)
//
#include <hip/hip_runtime.h>

// WindowAttention fused kernel for MI355X (gfx950).
// Strategy: one workgroup (256 thr = 4 waves) per window block b (grid=2048).
// Fully fused: qkv GEMM -> per-head scores (qk MFMA + rpe via 225-table
// GEMM+gather) -> softmax -> p@v MFMA + p@v_rpe via scatter+GEMM -> proj GEMM.
// All matmuls in bf16 MFMA 16x16x32, fp32 accumulate. Threshold is bf16-level.
//
// R1 fix: rpe_table head packing is [H,96]->split(3) (q_rpe=h*96+0..31,
// k_rpe=h*96+32.., v_rpe=h*96+64..), NOT the qkv [3,H,32] packing. Permute in
// wa_prep so the main kernel's [3,H,32] view stays unchanged.

#define SCALE 0.17677669529663687f   // 32^-0.5

typedef __attribute__((ext_vector_type(8))) __bf16 bf16x8;
typedef __attribute__((ext_vector_type(4))) float  f32x4;

__device__ __forceinline__ float bf2f(ushort u){
  union { unsigned int i; float f; } v; v.i = ((unsigned int)u) << 16; return v.f;
}
__device__ __forceinline__ ushort f2bf(float f){
  union { float f; unsigned int i; } v; v.f = f;
  unsigned int r = v.i + 0x7FFFu + ((v.i >> 16) & 1u);   // RNE
  return (ushort)(r >> 16);
}
__device__ __forceinline__ bf16x8 ld16(const ushort* p){          // 16B-aligned
  int4 v = *(const int4*)p;
  return __builtin_bit_cast(bf16x8, v);
}
__device__ __forceinline__ bf16x8 ld8(const ushort* p){           // 8B-aligned
  int2 lo = *(const int2*)p;
  int2 hi = *(const int2*)(p + 4);
  int4 v = make_int4(lo.x, lo.y, hi.x, hi.y);
  return __builtin_bit_cast(bf16x8, v);
}
__device__ __forceinline__ f32x4 mfma16(bf16x8 a, bf16x8 b, f32x4 c){
  return __builtin_amdgcn_mfma_f32_16x16x32_bf16(a, b, c, 0, 0, 0);
}
// REL_IDX computed on the fly: ip,jp in [0,64) positions of the 8x8 window
__device__ __forceinline__ int relidx(int ip, int jp){
  return ((ip >> 3) - (jp >> 3) + 7) * 15 + ((ip & 7) - (jp & 7) + 7);
}

// ---------------- prologue: bf16 conversions into workspace ----------------
// ws layout (ushorts): wb[49152] | pwb[16384] | rpeb[240*384] | tvt[4*32*240]
__global__ void wa_prep(const float* __restrict__ qkv_w,
                        const float* __restrict__ rpe,
                        const float* __restrict__ proj_w,
                        ushort* __restrict__ wb, ushort* __restrict__ pwb,
                        ushort* __restrict__ rpeb, ushort* __restrict__ tvt){
  int t = blockIdx.x * 256 + threadIdx.x;
  if (t < 49152) wb[t] = f2bf(qkv_w[t]);
  if (t < 16384) pwb[t] = f2bf(proj_w[t]);
  if (t < 92160){                 // rpeb [240][384] in [3,H,32] packing;
    int r = t / 384, c = t % 384; // source table is [H,96]=[H][3][32] packing
    int part = c >> 7, rem = c & 127, h = rem >> 5, cc = rem & 31;
    int srcc = h * 96 + part * 32 + cc;
    float v = (r < 225) ? rpe[r * 384 + srcc] * ((part == 0) ? SCALE : 1.0f) : 0.f;
    rpeb[t] = f2bf(v);
  }
  if (t < 30720){                 // tvt [h][c 32][r 240]  (v_rpe^T)
    int r = t % 240, hc = t / 240;
    int h = hc >> 5, c = hc & 31;
    float v = (r < 225) ? rpe[r * 384 + h * 96 + 64 + c] : 0.f;
    tvt[t] = f2bf(v);
  }
}

// ---------------- main fused kernel ----------------
__global__ __launch_bounds__(256, 1) void wa_attn(
    const float* __restrict__ x, const float* __restrict__ mask,
    const float* __restrict__ qkv_b, const float* __restrict__ proj_b,
    const ushort* __restrict__ wb, const ushort* __restrict__ pwb,
    const ushort* __restrict__ rpeb, const ushort* __restrict__ tvt,
    float* __restrict__ out)
{
  __shared__ __align__(16) ushort sm[81664];      // 163328 B of 163840
  ushort* xs  = sm;               // [128][136] bf16 x
  ushort* qs  = sm + 17408;       // [128][52]  q (pre-scaled)
  ushort* ks  = sm + 24064;       // [128][52]  k
  ushort* vts = sm + 30720;       // [32][136]  v transposed [c][token]
  ushort* uvs = sm + 35072;       // [128][228] U_q / V_k / W overlay
  ushort* ps  = sm + 64256;       // [128][136] p (softmax), later att_out

  const int tid  = threadIdx.x;
  const int lane = tid & 63;
  const int wv   = tid >> 6;
  const int m16  = lane & 15;
  const int q4   = lane >> 4;
  const int b    = blockIdx.x;
  const int wi   = b & 127;                       // window index for mask
  const int row0 = wv * 32;                       // this wave's M band
  const float* mrow = mask + (size_t)wi * 16384;

  // ---- P0: stage x -> bf16 LDS (2 threads per row)
  {
    int r = tid >> 1, hf = tid & 1;
    const float* src = x + (size_t)b * 16384 + r * 128 + hf * 64;
    ushort* dst = xs + r * 136 + hf * 64;
#pragma unroll
    for (int it = 0; it < 16; ++it){
      float4 f = *(const float4*)(src + it * 4);
      dst[it*4+0] = f2bf(f.x); dst[it*4+1] = f2bf(f.y);
      dst[it*4+2] = f2bf(f.z); dst[it*4+3] = f2bf(f.w);
    }
  }
  __syncthreads();

  f32x4 ao[4][2][2];                              // per-head attn-out accum

#pragma unroll
  for (int h = 0; h < 4; ++h){
    // ---- P1: qkv GEMM  [128,128]@[128,96] for head h
    {
      f32x4 aqk[2][6];
#pragma unroll
      for (int mt = 0; mt < 2; ++mt)
#pragma unroll
        for (int nt = 0; nt < 6; ++nt) aqk[mt][nt] = f32x4{0.f,0.f,0.f,0.f};
#pragma unroll
      for (int kk = 0; kk < 4; ++kk){
        bf16x8 a[2];
#pragma unroll
        for (int mt = 0; mt < 2; ++mt)
          a[mt] = ld16(xs + (row0 + mt*16 + m16)*136 + kk*32 + q4*8);
#pragma unroll
        for (int nt = 0; nt < 6; ++nt){
          int obase = (nt >> 1)*128 + h*32 + (nt & 1)*16;
          bf16x8 bf = ld16(wb + (obase + m16)*128 + kk*32 + q4*8);
#pragma unroll
          for (int mt = 0; mt < 2; ++mt) aqk[mt][nt] = mfma16(a[mt], bf, aqk[mt][nt]);
        }
      }
#pragma unroll
      for (int nt = 0; nt < 6; ++nt){
        int part = nt >> 1;
        int colb = (nt & 1)*16 + m16;
        float bias = qkv_b[part*128 + h*32 + colb];
#pragma unroll
        for (int mt = 0; mt < 2; ++mt){
          int rb = row0 + mt*16 + q4*4;
#pragma unroll
          for (int r = 0; r < 4; ++r){
            float v = aqk[mt][nt][r] + bias;
            if (part == 0)      qs[(rb+r)*52 + colb] = f2bf(v * SCALE);
            else if (part == 1) ks[(rb+r)*52 + colb] = f2bf(v);
            else                vts[colb*136 + rb + r] = f2bf(v);
          }
        }
      }
    }
    // ---- P2: U_q[i,r] = q[i,:]·k_rpe[r,:]   (own-band rows only)
    bf16x8 afq[2];
#pragma unroll
    for (int mt = 0; mt < 2; ++mt)
      afq[mt] = ld8(qs + (row0 + mt*16 + m16)*52 + q4*8);
#pragma unroll
    for (int nt = 0; nt < 15; ++nt){
      bf16x8 bf = ld16(rpeb + (nt*16 + m16)*384 + 128 + h*32 + q4*8);
#pragma unroll
      for (int mt = 0; mt < 2; ++mt){
        f32x4 d = mfma16(afq[mt], bf, f32x4{0.f,0.f,0.f,0.f});
        int col = nt*16 + m16;
        if (col < 225){
          int rb = row0 + mt*16 + q4*4;
#pragma unroll
          for (int r = 0; r < 4; ++r) uvs[(rb+r)*228 + col] = f2bf(d[r]);
        }
      }
    }
    __syncthreads();   // (A) qkv + U_q visible

    // ---- P3: qk GEMM + assembly pass A (mask + U_q gather)
    f32x4 S[2][8];
#pragma unroll
    for (int nt = 0; nt < 8; ++nt){
      bf16x8 bk = ld8(ks + (nt*16 + m16)*52 + q4*8);
#pragma unroll
      for (int mt = 0; mt < 2; ++mt) S[mt][nt] = mfma16(afq[mt], bk, f32x4{0.f,0.f,0.f,0.f});
    }
#pragma unroll
    for (int mt = 0; mt < 2; ++mt){
      int rb = row0 + mt*16 + q4*4;
#pragma unroll
      for (int nt = 0; nt < 8; ++nt){
        int j = nt*16 + m16, jp = j >> 1;
#pragma unroll
        for (int r = 0; r < 4; ++r){
          int i = rb + r;
          S[mt][nt][r] += mrow[i*128 + j] + bf2f(uvs[i*228 + relidx(i>>1, jp)]);
        }
      }
    }
    // ---- P4: V_k[j,r] = k[j,:]·(scale·q_rpe[r,:])  (own-band rows; disjoint)
    {
      bf16x8 afk[2];
#pragma unroll
      for (int mt = 0; mt < 2; ++mt)
        afk[mt] = ld8(ks + (row0 + mt*16 + m16)*52 + q4*8);
#pragma unroll
      for (int nt = 0; nt < 15; ++nt){
        bf16x8 bf = ld16(rpeb + (nt*16 + m16)*384 + h*32 + q4*8);
#pragma unroll
        for (int mt = 0; mt < 2; ++mt){
          f32x4 d = mfma16(afk[mt], bf, f32x4{0.f,0.f,0.f,0.f});
          int col = nt*16 + m16;
          if (col < 225){
            int rb = row0 + mt*16 + q4*4;
#pragma unroll
            for (int r = 0; r < 4; ++r) uvs[(rb+r)*228 + col] = f2bf(d[r]);
          }
        }
      }
    }
    __syncthreads();   // (B) V_k visible to all waves

    // ---- P5: pass B (V_k gather) + softmax + write p
#pragma unroll
    for (int mt = 0; mt < 2; ++mt){
      int rb = row0 + mt*16 + q4*4;
#pragma unroll
      for (int nt = 0; nt < 8; ++nt){
        int j = nt*16 + m16, jp = j >> 1;
#pragma unroll
        for (int r = 0; r < 4; ++r)
          S[mt][nt][r] += bf2f(uvs[j*228 + relidx((rb+r)>>1, jp)]);
      }
    }
#pragma unroll
    for (int mt = 0; mt < 2; ++mt){
      int rb = row0 + mt*16 + q4*4;
#pragma unroll
      for (int r = 0; r < 4; ++r){
        float mx = S[mt][0][r];
#pragma unroll
        for (int nt = 1; nt < 8; ++nt) mx = fmaxf(mx, S[mt][nt][r]);
        mx = fmaxf(mx, __shfl_xor(mx, 1));
        mx = fmaxf(mx, __shfl_xor(mx, 2));
        mx = fmaxf(mx, __shfl_xor(mx, 4));
        mx = fmaxf(mx, __shfl_xor(mx, 8));
        float e[8]; float sum = 0.f;
#pragma unroll
        for (int nt = 0; nt < 8; ++nt){
          e[nt] = exp2f((S[mt][nt][r] - mx) * 1.44269504089f); sum += e[nt];
        }
        sum += __shfl_xor(sum, 1);
        sum += __shfl_xor(sum, 2);
        sum += __shfl_xor(sum, 4);
        sum += __shfl_xor(sum, 8);
        float inv = __builtin_amdgcn_rcpf(sum);
        int i = rb + r;
#pragma unroll
        for (int nt = 0; nt < 8; ++nt) ps[i*136 + nt*16 + m16] = f2bf(e[nt] * inv);
      }
    }
    __syncthreads();   // (C) p visible; uvs free for W

    // ---- P6: out1 = p @ v
#pragma unroll
    for (int mt = 0; mt < 2; ++mt)
#pragma unroll
      for (int nt = 0; nt < 2; ++nt) ao[h][mt][nt] = f32x4{0.f,0.f,0.f,0.f};
#pragma unroll
    for (int kk = 0; kk < 4; ++kk){
      bf16x8 ap[2];
#pragma unroll
      for (int mt = 0; mt < 2; ++mt)
        ap[mt] = ld16(ps + (row0 + mt*16 + m16)*136 + kk*32 + q4*8);
#pragma unroll
      for (int nt = 0; nt < 2; ++nt){
        bf16x8 bv = ld16(vts + (nt*16 + m16)*136 + kk*32 + q4*8);
#pragma unroll
        for (int mt = 0; mt < 2; ++mt) ao[h][mt][nt] = mfma16(ap[mt], bv, ao[h][mt][nt]);
      }
    }
    // ---- P7: W[i,r] = p2 scatter (injective per row -> plain writes)
    {
      uint* uz = (uint*)uvs;
#pragma unroll
      for (int it = 0; it < 57; ++it) uz[it*256 + tid] = 0;   // 14592 uints
    }
    __syncthreads();   // (D) zeros done
#pragma unroll
    for (int it = 0; it < 32; ++it){
      int flat = it*256 + tid;
      int i = flat >> 6, jp = flat & 63;
      uint pp = *(const uint*)(ps + i*136 + jp*2);
      float p2 = bf2f((ushort)(pp & 0xFFFFu)) + bf2f((ushort)(pp >> 16));
      uvs[i*228 + relidx(i >> 1, jp)] = f2bf(p2);
    }
    __syncthreads();   // (E) W done
    // out2 = W @ Tv : 7 MFMA K-steps (r=0..223) + scalar fixup r=224
#pragma unroll
    for (int kk = 0; kk < 7; ++kk){
      bf16x8 aw[2];
#pragma unroll
      for (int mt = 0; mt < 2; ++mt)
        aw[mt] = ld8(uvs + (row0 + mt*16 + m16)*228 + kk*32 + q4*8);
#pragma unroll
      for (int nt = 0; nt < 2; ++nt){
        bf16x8 bt = ld16(tvt + (h*32 + nt*16 + m16)*240 + kk*32 + q4*8);
#pragma unroll
        for (int mt = 0; mt < 2; ++mt) ao[h][mt][nt] = mfma16(aw[mt], bt, ao[h][mt][nt]);
      }
    }
#pragma unroll
    for (int nt = 0; nt < 2; ++nt){
      float tvv = bf2f(tvt[(h*32 + nt*16 + m16)*240 + 224]);
#pragma unroll
      for (int mt = 0; mt < 2; ++mt){
        int rb = row0 + mt*16 + q4*4;
#pragma unroll
        for (int r = 0; r < 4; ++r)
          ao[h][mt][nt][r] += bf2f(uvs[(rb+r)*228 + 224]) * tvv;
      }
    }
  } // heads

  // ---- P8: stage att_out (own rows, own wave) then proj GEMM
#pragma unroll
  for (int h = 0; h < 4; ++h)
#pragma unroll
    for (int mt = 0; mt < 2; ++mt){
      int rb = row0 + mt*16 + q4*4;
#pragma unroll
      for (int nt = 0; nt < 2; ++nt){
        int col = h*32 + nt*16 + m16;
#pragma unroll
        for (int r = 0; r < 4; ++r) ps[(rb+r)*136 + col] = f2bf(ao[h][mt][nt][r]);
      }
    }
  // same-wave write->read: compiler inserts lgkmcnt; no barrier needed
  f32x4 po[2][8];
#pragma unroll
  for (int mt = 0; mt < 2; ++mt)
#pragma unroll
    for (int nt = 0; nt < 8; ++nt) po[mt][nt] = f32x4{0.f,0.f,0.f,0.f};
#pragma unroll
  for (int kk = 0; kk < 4; ++kk){
    bf16x8 aA[2];
#pragma unroll
    for (int mt = 0; mt < 2; ++mt)
      aA[mt] = ld16(ps + (row0 + mt*16 + m16)*136 + kk*32 + q4*8);
#pragma unroll
    for (int nt = 0; nt < 8; ++nt){
      bf16x8 bw = ld16(pwb + (nt*16 + m16)*128 + kk*32 + q4*8);
#pragma unroll
      for (int mt = 0; mt < 2; ++mt) po[mt][nt] = mfma16(aA[mt], bw, po[mt][nt]);
    }
  }
  float* outb = out + (size_t)b * 16384;
#pragma unroll
  for (int nt = 0; nt < 8; ++nt){
    int o = nt*16 + m16;
    float bias = proj_b[o];
#pragma unroll
    for (int mt = 0; mt < 2; ++mt){
      int rb = row0 + mt*16 + q4*4;
#pragma unroll
      for (int r = 0; r < 4; ++r) outb[(rb+r)*128 + o] = po[mt][nt][r] + bias;
    }
  }
}

extern "C" void kernel_launch(void* const* d_in, const int* in_sizes, int n_in,
                              void* d_out, int out_size, void* d_ws, size_t ws_size,
                              hipStream_t stream){
  (void)in_sizes; (void)n_in; (void)out_size; (void)ws_size;
  const float* x      = (const float*)d_in[0];
  const float* mask   = (const float*)d_in[1];
  const float* qkv_w  = (const float*)d_in[2];
  const float* qkv_b  = (const float*)d_in[3];
  const float* rpe    = (const float*)d_in[4];
  const float* proj_w = (const float*)d_in[5];
  const float* proj_b = (const float*)d_in[6];

  ushort* wb   = (ushort*)d_ws;            // 49152
  ushort* pwb  = wb + 49152;               // 16384
  ushort* rpeb = pwb + 16384;              // 240*384 = 92160
  ushort* tvt  = rpeb + 92160;             // 4*32*240 = 30720  (total 376832 B)

  wa_prep<<<360, 256, 0, stream>>>(qkv_w, rpe, proj_w, wb, pwb, rpeb, tvt);
  wa_attn<<<2048, 256, 0, stream>>>(x, mask, qkv_b, proj_b, wb, pwb, rpeb, tvt,
                                    (float*)d_out);
}